// Round 11
// baseline (467.514 us; speedup 1.0000x reference)
//
#include <hip/hip_runtime.h>
#include <stdint.h>

typedef unsigned short ushort_t;
typedef __attribute__((ext_vector_type(8))) short bf16x8;   // 8 bf16 = 4 VGPRs
typedef __attribute__((ext_vector_type(4))) float f32x4;

__device__ __forceinline__ ushort_t f2bf(float f) {
  union { float f; uint32_t u; } v; v.f = f;
  uint32_t u = v.u;
  u += 0x7FFFu + ((u >> 16) & 1u);   // RNE
  return (ushort_t)(u >> 16);
}
__device__ __forceinline__ float bf2f(ushort_t h) {
  union { uint32_t u; float f; } v; v.u = ((uint32_t)h) << 16;
  return v.f;
}
__device__ __forceinline__ void gl2lds16(const void* g, void* l) {
  __builtin_amdgcn_global_load_lds(
      (__attribute__((address_space(1))) void*)(uintptr_t)g,
      (__attribute__((address_space(3))) void*)(uint32_t)(uintptr_t)l,
      16, 0, 0);
}

// Pipeline (R11): kv = K^T V = Wk^T (Xr^T Xi) Wv, 5 launches:
//   prep2: W^T bf16 + X fp32->bf16 straight (d_out) AND transposed (ws)
//   gqp  : FUSED { gq: Q = (Xr@Wqr).*(Xi@Wqi), 96KB 1-boundary/ks |
//                  gpart: G[b] = Xr_b^T Xi_b, K=4096 full, fp32 acc -> bf16 }
//          (no split-K partials, no reduce; gpart blocks backfill gq's tail)
//   h1k x2: H = Wv^T G ; KVT = H Wk^T  (256x128 tiles via gemm256x128)
//   fin  : Out = Q @ KVT^T
// All K-loops: R7-verified skeleton { vmcnt(0)+lgkm(0)+barrier; prefetch next;
// read frags; MFMA }, swizzle kg = chunk ^ ((row>>1)&3) (conflict-free, R7 PMC),
// tail-safe conditional prefetch.

// ---------- 256x128, BK=32, 8-wave GEMM core (gpart / h1k / fin) ----------
__device__ __forceinline__ void gemm256x128(
    const ushort_t* __restrict__ A, int lda,
    const ushort_t* __restrict__ Bt, int ldb,
    int m0, int n0, int K, char* __restrict__ smem,
    f32x4 (&acc)[4][4]) {
  const int t = threadIdx.x;
  const int nt = K >> 5;
  const int rowS = t >> 2;
  const int kgS = (t & 3) ^ ((t >> 3) & 3);
  const ushort_t* a0 = A + (size_t)(m0 + rowS) * lda + kgS * 8;
  const ushort_t* a1 = a0 + (size_t)128 * lda;
  const ushort_t* b0 = Bt + (size_t)(n0 + rowS) * ldb + kgS * 8;
  const int d0 = t * 16;
  const int lane = t & 63, wid = t >> 6;
  const int wm = wid >> 1, wn = wid & 1;
  const int lr = lane & 15, lq = lane >> 4;
  const int o = lr * 64 + ((lq ^ ((lr >> 1) & 3)) << 4);
  const int aW = wm * 4096;
  const int bW = 16384 + wn * 4096;

#define STAGE(tt, buf) do { \
    char* s = smem + (buf); \
    gl2lds16(a0 + (tt) * 32, s + d0); \
    gl2lds16(a1 + (tt) * 32, s + 8192 + d0); \
    gl2lds16(b0 + (tt) * 32, s + 16384 + d0); \
  } while (0)

  bf16x8 aF[4], bF[4];
  STAGE(0, 0);
  for (int tt = 0; tt < nt; ++tt) {
    asm volatile("s_waitcnt vmcnt(0) lgkmcnt(0)\n\ts_barrier" ::: "memory");
    const int cb = (tt & 1) ? 24576 : 0;
    if (tt + 1 < nt) STAGE(tt + 1, (tt & 1) ? 0 : 24576);
    const char* base = smem + cb;
    #pragma unroll
    for (int mi = 0; mi < 4; ++mi)
      aF[mi] = *(const bf16x8*)(base + aW + mi * 1024 + o);
    #pragma unroll
    for (int ni = 0; ni < 4; ++ni)
      bF[ni] = *(const bf16x8*)(base + bW + ni * 1024 + o);
    __builtin_amdgcn_s_setprio(1);
    #pragma unroll
    for (int mi = 0; mi < 4; ++mi)
      #pragma unroll
      for (int ni = 0; ni < 4; ++ni)
        acc[mi][ni] = __builtin_amdgcn_mfma_f32_16x16x32_bf16(aF[mi], bF[ni], acc[mi][ni], 0, 0, 0);
    __builtin_amdgcn_s_setprio(0);
  }
#undef STAGE
}

// ---- gqp: fused gq (bid<512) + gpart (bid>=512), 512 thr, 96KB dsmem ----
// gq branch: 256x128 tile, ONE boundary per ks: stage {Ar,Br,Ai,Bi}(ks+1)
//   into alt 48KB buffer (12 gl2lds), read 16 frags, 32 MFMA.  R4 skeleton
//   (full drain per boundary + conditional prefetch) -> tail-safe.
// gpart branch: G[b] = XrT_b @ XiT_b^T with K=4096 (no split-K), fp32 acc,
//   bf16 store to G.  Uses gemm256x128 unchanged (96KB alloc, 48KB used).
__global__ __launch_bounds__(512, 1) void gqp(
    const ushort_t* __restrict__ Xr, const ushort_t* __restrict__ Xi,
    const ushort_t* __restrict__ Wr, const ushort_t* __restrict__ Wi,
    ushort_t* __restrict__ Q,
    const ushort_t* __restrict__ XrT, const ushort_t* __restrict__ XiT,
    ushort_t* __restrict__ G) {
  extern __shared__ char smem[];
  const int bid = blockIdx.x;
  const int t = threadIdx.x;
  const int lane = t & 63, wid = t >> 6;
  const int wm = wid >> 1, wn = wid & 1;
  const int lr = lane & 15, lq = lane >> 4;
  const int rowS = t >> 2;
  const int kgS = (t & 3) ^ ((t >> 3) & 3);
  const int d0 = t * 16;
  const int o = lr * 64 + ((lq ^ ((lr >> 1) & 3)) << 4);

  if (bid >= 512) {
    // ---------- gpart: full-K per-batch G ----------
    const int j = bid - 512;                  // 0..127
    const int b = j >> 5, mn = j & 31;
    const int m0 = (mn >> 3) * 256, n0 = (mn & 7) * 128;
    const ushort_t* A = XrT + ((size_t)b << 22);
    const ushort_t* Bt = XiT + ((size_t)b << 22);
    f32x4 acc[4][4] = {};
    gemm256x128(A, 4096, Bt, 4096, m0, n0, 4096, smem, acc);
    ushort_t* C = G + ((size_t)b << 20);
    #pragma unroll
    for (int mi = 0; mi < 4; ++mi) {
      int rbase = m0 + wm * 64 + mi * 16 + lq * 4;
      #pragma unroll
      for (int ni = 0; ni < 4; ++ni) {
        int c = n0 + wn * 64 + ni * 16 + lr;
        #pragma unroll
        for (int r = 0; r < 4; ++r)
          C[(size_t)(rbase + r) * 1024 + c] = f2bf(acc[mi][ni][r]);
      }
    }
    return;
  }

  // ---------- gq: dual GEMM, 1 boundary per ks ----------
  const int xcd = bid & 7, i = bid >> 3;
  const int m0 = (xcd * 8 + (i >> 3)) * 256;
  const int n0 = (i & 7) * 128;
  const ushort_t* ar0 = Xr + (size_t)(m0 + rowS) * 1024 + kgS * 8;
  const ushort_t* ar1 = ar0 + (size_t)(128 * 1024);
  const ushort_t* ai0 = Xi + (size_t)(m0 + rowS) * 1024 + kgS * 8;
  const ushort_t* ai1 = ai0 + (size_t)(128 * 1024);
  const ushort_t* br0 = Wr + (size_t)(n0 + rowS) * 1024 + kgS * 8;
  const ushort_t* bi0 = Wi + (size_t)(n0 + rowS) * 1024 + kgS * 8;

#define STGALL(ks, buf) do { \
    char* s = smem + (buf); \
    gl2lds16(ar0 + (ks) * 32, s + d0); \
    gl2lds16(ar1 + (ks) * 32, s + 8192 + d0); \
    gl2lds16(br0 + (ks) * 32, s + 16384 + d0); \
    gl2lds16(ai0 + (ks) * 32, s + 24576 + d0); \
    gl2lds16(ai1 + (ks) * 32, s + 32768 + d0); \
    gl2lds16(bi0 + (ks) * 32, s + 40960 + d0); \
  } while (0)

  f32x4 accR[4][4] = {}, accI[4][4] = {};
  STGALL(0, 0);
  for (int ks = 0; ks < 32; ++ks) {
    asm volatile("s_waitcnt vmcnt(0) lgkmcnt(0)\n\ts_barrier" ::: "memory");
    const int cb = (ks & 1) ? 49152 : 0;
    if (ks + 1 < 32) STGALL(ks + 1, (ks & 1) ? 0 : 49152);
    const char* base = smem + cb;
    bf16x8 aR[4], bR[4], aI[4], bI[4];
    #pragma unroll
    for (int mi = 0; mi < 4; ++mi) {
      aR[mi] = *(const bf16x8*)(base + wm * 4096 + mi * 1024 + o);
      aI[mi] = *(const bf16x8*)(base + 24576 + wm * 4096 + mi * 1024 + o);
    }
    #pragma unroll
    for (int ni = 0; ni < 4; ++ni) {
      bR[ni] = *(const bf16x8*)(base + 16384 + wn * 4096 + ni * 1024 + o);
      bI[ni] = *(const bf16x8*)(base + 40960 + wn * 4096 + ni * 1024 + o);
    }
    __builtin_amdgcn_s_setprio(1);
    #pragma unroll
    for (int mi = 0; mi < 4; ++mi)
      #pragma unroll
      for (int ni = 0; ni < 4; ++ni) {
        accR[mi][ni] = __builtin_amdgcn_mfma_f32_16x16x32_bf16(aR[mi], bR[ni], accR[mi][ni], 0, 0, 0);
        accI[mi][ni] = __builtin_amdgcn_mfma_f32_16x16x32_bf16(aI[mi], bI[ni], accI[mi][ni], 0, 0, 0);
      }
    __builtin_amdgcn_s_setprio(0);
  }
#undef STGALL

  #pragma unroll
  for (int mi = 0; mi < 4; ++mi) {
    int rbase = m0 + wm * 64 + mi * 16 + lq * 4;
    #pragma unroll
    for (int ni = 0; ni < 4; ++ni) {
      int c = n0 + wn * 64 + ni * 16 + lr;
      #pragma unroll
      for (int r = 0; r < 4; ++r)
        Q[(size_t)(rbase + r) * 1024 + c] = f2bf(accR[mi][ni][r] * accI[mi][ni][r]);
    }
  }
}

// ---- h1k: per-batch C[1024][1024] = A @ Bt^T, 256x128 tiles, grid 128 ----
__global__ __launch_bounds__(512, 2) void h1k(
    const ushort_t* __restrict__ Abase, int aStride,
    const ushort_t* __restrict__ Btbase, int btStride,
    ushort_t* __restrict__ Cbase) {
  extern __shared__ char smem[];
  const int bid = blockIdx.x;
  const int b = bid >> 5, mn = bid & 31;
  const int m0 = (mn >> 3) * 256, n0 = (mn & 7) * 128;
  const ushort_t* A = Abase + (size_t)b * (size_t)aStride;
  const ushort_t* Bt = Btbase + (size_t)b * (size_t)btStride;
  f32x4 acc[4][4] = {};
  gemm256x128(A, 1024, Bt, 1024, m0, n0, 1024, smem, acc);

  const int t = threadIdx.x, lane = t & 63, wid = t >> 6;
  const int wm = wid >> 1, wn = wid & 1;
  const int lr = lane & 15, lq = lane >> 4;
  ushort_t* C = Cbase + ((size_t)b << 20);
  #pragma unroll
  for (int mi = 0; mi < 4; ++mi) {
    int rbase = m0 + wm * 64 + mi * 16 + lq * 4;
    #pragma unroll
    for (int ni = 0; ni < 4; ++ni) {
      int c = n0 + wn * 64 + ni * 16 + lr;
      #pragma unroll
      for (int r = 0; r < 4; ++r)
        C[(size_t)(rbase + r) * 1024 + c] = f2bf(acc[mi][ni][r]);
    }
  }
}

// ---- fin: Out[n][e] = sum_d Q[n][d] * KVT[b][e][d], fp32 out, grid 512 ----
__global__ __launch_bounds__(512, 4) void fin8(
    const ushort_t* __restrict__ Q, const ushort_t* __restrict__ KVT,
    float* __restrict__ Out) {
  extern __shared__ char smem[];
  const int bid = blockIdx.x;
  const int xcd = bid & 7, i = bid >> 3;        // i: 0..63
  const int m0 = (xcd * 8 + (i >> 3)) * 256;
  const int n0 = (i & 7) * 128;
  const int b = m0 >> 12;
  f32x4 acc[4][4] = {};
  gemm256x128(Q, 1024, KVT + ((size_t)b << 20), 1024, m0, n0, 1024, smem, acc);

  const int t = threadIdx.x, lane = t & 63, wid = t >> 6;
  const int wm = wid >> 1, wn = wid & 1;
  const int lr = lane & 15, lq = lane >> 4;
  #pragma unroll
  for (int mi = 0; mi < 4; ++mi) {
    int rbase = m0 + wm * 64 + mi * 16 + lq * 4;
    #pragma unroll
    for (int ni = 0; ni < 4; ++ni) {
      int c = n0 + wn * 64 + ni * 16 + lr;
      #pragma unroll
      for (int r = 0; r < 4; ++r)
        Out[(size_t)(rbase + r) * 1024 + c] = acc[mi][ni][r];
    }
  }
}

// ---- prep2: W^T (32x32 tiles) + X one-pass straight+transposed (64x64, wide IO) ----
__global__ __launch_bounds__(256) void prep2(
    const float* __restrict__ xr, const float* __restrict__ xi,
    const float* w0, const float* w1, const float* w2, const float* w3,
    ushort_t* __restrict__ xrb, ushort_t* __restrict__ xib,
    ushort_t* __restrict__ xrT, ushort_t* __restrict__ xiT,
    ushort_t* o0, ushort_t* o1, ushort_t* o2, ushort_t* o3) {
  const int bid = blockIdx.x;
  const int t = threadIdx.x;
  if (bid < 4096) {
    __shared__ float tile[32][33];
    const int tx = t & 31, ty = t >> 5;   // (32, 8)
    const float* W; ushort_t* O;
    switch (bid >> 10) {
      case 0: W = w0; O = o0; break;
      case 1: W = w1; O = o1; break;
      case 2: W = w2; O = o2; break;
      default: W = w3; O = o3; break;
    }
    const int within = bid & 1023;
    const int bx = (within & 31) * 32, by = (within >> 5) * 32;
    #pragma unroll
    for (int k = 0; k < 32; k += 8)
      tile[ty + k][tx] = W[(size_t)(by + ty + k) * 1024 + bx + tx];
    __syncthreads();
    #pragma unroll
    for (int k = 0; k < 32; k += 8)
      O[(size_t)(bx + ty + k) * 1024 + by + tx] = f2bf(tile[tx][ty + k]);
  } else {
    __shared__ float tx64[64][65];        // +1 pad: col reads 2-way max
    const int xb = bid - 4096;            // 0..8191
    const int tensor = xb >> 12;          // 4096 tiles each
    const int within = xb & 4095;
    const int n0 = (within >> 4) * 64;    // 256 n-tiles
    const int d0g = (within & 15) * 64;   // 16 d-tiles
    const float* src = tensor ? xi : xr;
    ushort_t* dstS = tensor ? xib : xrb;
    ushort_t* dstT = tensor ? xiT : xrT;
    const int r = t >> 2;                 // 0..63
    const int c4 = (t & 3) * 4;
    #pragma unroll
    for (int p = 0; p < 4; ++p) {
      float4 v = *(const float4*)&src[(size_t)(n0 + r) * 1024 + d0g + c4 + p * 16];
      tx64[r][c4 + p * 16 + 0] = v.x;
      tx64[r][c4 + p * 16 + 1] = v.y;
      tx64[r][c4 + p * 16 + 2] = v.z;
      tx64[r][c4 + p * 16 + 3] = v.w;
    }
    __syncthreads();
    {   // straight: row r, 16 cols per thread, bf16x8 stores
      const int c0 = (t & 3) * 16;
      ushort_t tmp[16];
      #pragma unroll
      for (int j = 0; j < 16; ++j) tmp[j] = f2bf(tx64[r][c0 + j]);
      ushort_t* p = &dstS[(size_t)(n0 + r) * 1024 + d0g + c0];
      *(bf16x8*)&p[0] = *(const bf16x8*)&tmp[0];
      *(bf16x8*)&p[8] = *(const bf16x8*)&tmp[8];
    }
    {   // transposed: d-row r, 16 n per thread, bf16x8 stores
      const int nb = (t & 3) * 16;
      ushort_t tmp[16];
      #pragma unroll
      for (int j = 0; j < 16; ++j) tmp[j] = f2bf(tx64[nb + j][r]);
      const int b = n0 >> 12, nn = n0 & 4095;
      ushort_t* p = &dstT[((size_t)b << 22) + (size_t)(d0g + r) * 4096 + nn + nb];
      *(bf16x8*)&p[0] = *(const bf16x8*)&tmp[0];
      *(bf16x8*)&p[8] = *(const bf16x8*)&tmp[8];
    }
  }
}

extern "C" void kernel_launch(void* const* d_in, const int* in_sizes, int n_in,
                              void* d_out, int out_size, void* d_ws, size_t ws_size,
                              hipStream_t stream) {
  const float* xr  = (const float*)d_in[0];
  const float* xi  = (const float*)d_in[1];
  const float* wqr = (const float*)d_in[2];
  const float* wqi = (const float*)d_in[3];
  const float* wk  = (const float*)d_in[4];
  const float* wv  = (const float*)d_in[5];

  char* ws = (char*)d_ws;
  const size_t MB = 1024ull * 1024ull;
  ushort_t* WtQR = (ushort_t*)(ws + 0 * MB);    // Wqr^T [1024e][1024d]
  ushort_t* WtQI = (ushort_t*)(ws + 2 * MB);    // Wqi^T
  ushort_t* WtK  = (ushort_t*)(ws + 4 * MB);    // Wk^T
  ushort_t* WtV  = (ushort_t*)(ws + 6 * MB);    // Wv^T
  ushort_t* XrT  = (ushort_t*)(ws + 8 * MB);    // [4][1024d][4096n]; dead after gqp
  ushort_t* XiT  = (ushort_t*)(ws + 40 * MB);   // [4][1024e][4096n]; dead after gqp
  ushort_t* Q    = (ushort_t*)(ws + 72 * MB);   // gated query bf16 [16384][1024]
  ushort_t* G    = (ushort_t*)(ws + 104 * MB);  // [4][1024][1024] bf16 8MB
  ushort_t* H    = (ushort_t*)(ws + 8 * MB);    // overlay XrT (dead after gqp)
  ushort_t* KVT  = (ushort_t*)(ws + 16 * MB);   // overlay XrT
  ushort_t* Xrb  = (ushort_t*)d_out;            // bf16 [16384][1024] (phase 1)
  ushort_t* Xib  = (ushort_t*)((char*)d_out + 32 * MB);

  static bool inited = false;
  if (!inited) {
    inited = true;
    hipFuncSetAttribute((const void*)&gqp,  hipFuncAttributeMaxDynamicSharedMemorySize, 98304);
    hipFuncSetAttribute((const void*)&h1k,  hipFuncAttributeMaxDynamicSharedMemorySize, 49152);
    hipFuncSetAttribute((const void*)&fin8, hipFuncAttributeMaxDynamicSharedMemorySize, 49152);
  }

  prep2<<<12288, 256, 0, stream>>>(xr, xi, wqr, wqi, wk, wv,
                                   Xrb, Xib, XrT, XiT, WtQR, WtQI, WtK, WtV);
  gqp<<<640, 512, 98304, stream>>>(Xrb, Xib, WtQR, WtQI, Q, XrT, XiT, G);
  h1k<<<128, 512, 49152, stream>>>(WtV, 0, G, 1 << 20, H);    // H = Wv^T G
  h1k<<<128, 512, 49152, stream>>>(H, 1 << 20, WtK, 0, KVT);  // KVT = H Wk^T
  fin8<<<512, 512, 49152, stream>>>(Q, KVT, (float*)d_out);
}

// Round 12
// 388.178 us; speedup vs baseline: 1.2044x; 1.2044x over previous
//
#include <hip/hip_runtime.h>
#include <stdint.h>

typedef unsigned short ushort_t;
typedef __attribute__((ext_vector_type(8))) short bf16x8;   // 8 bf16 = 4 VGPRs
typedef __attribute__((ext_vector_type(4))) float f32x4;

__device__ __forceinline__ ushort_t f2bf(float f) {
  union { float f; uint32_t u; } v; v.f = f;
  uint32_t u = v.u;
  u += 0x7FFFu + ((u >> 16) & 1u);   // RNE
  return (ushort_t)(u >> 16);
}
__device__ __forceinline__ float bf2f(ushort_t h) {
  union { uint32_t u; float f; } v; v.u = ((uint32_t)h) << 16;
  return v.f;
}
__device__ __forceinline__ void gl2lds16(const void* g, void* l) {
  __builtin_amdgcn_global_load_lds(
      (__attribute__((address_space(1))) void*)(uintptr_t)g,
      (__attribute__((address_space(3))) void*)(uint32_t)(uintptr_t)l,
      16, 0, 0);
}

// ==================== 256x256 tile, BK=64, 8-wave, 8-phase GEMM ====================
// C = A * Bt^T.  LDS (128 KiB dynamic): A[2buf][2half][128][64] | B[same].
// Chunk-XOR swizzle (16B chunk ^= row&7) on BOTH stage-source and ds_read.
// ONE barrier per phase (lgkmcnt(0)+s_barrier, memory-clobbered asm).
// vmcnt LEDGER (per wave, 2 loads per STG):
//   steady state at ph4/ph8 vmcnt(4): 12 outstanding = [A(t+1)x4 carry,
//   B(t+1)x4, A(t+2)x4]; drain-to-4 retires exactly tile t+1 before its reads.
// TAIL (peeled last iteration): ph3/ph4 A-stages don't exist, so the counted
// wait would leave B(nt-1) in flight when ph5 reads it (the round-2 bug).
// The tail instead does vmcnt(0) at ph4 — no later stages, so a full drain is
// free and guarantees tile nt-1 resident.  Main loop stages are unconditional
// (all indices provably < nt).  nt must be even and >= 4 (nt=16 here).
// [Session best: this exact source measured 384.8 us (R3) and 385.1 us (R5).]
__device__ __forceinline__ void gemm256(
    const ushort_t* __restrict__ A, int lda,
    const ushort_t* __restrict__ Bt, int ldb,
    int m0, int n0, int K, char* __restrict__ smem,
    f32x4 (&acc)[8][4]) {
  const int t = threadIdx.x;
  const int lane = t & 63, wid = t >> 6;
  const int wm = wid >> 2, wn = wid & 3;      // 2 M-waves x 4 N-waves
  const int lr = lane & 15, lq = lane >> 4;
  const int nt = K >> 6;

  // staging: half-tile = 128 rows x 64 k = 16KB; 512 thr x 2 x 16B
  const int row0 = t >> 3, row1 = (512 + t) >> 3;
  const int kg0 = (t & 7) ^ (row0 & 7), kg1 = (t & 7) ^ (row1 & 7);
  const ushort_t* a0 = A + (size_t)(m0 + row0) * lda + kg0 * 8;
  const ushort_t* a1 = A + (size_t)(m0 + row1) * lda + kg1 * 8;
  const ushort_t* b0 = Bt + (size_t)(n0 + row0) * ldb + kg0 * 8;
  const ushort_t* b1 = Bt + (size_t)(n0 + row1) * ldb + kg1 * 8;
  const int d0 = t * 16, d1 = (512 + t) * 16;

  const int o0 = lr * 128 + ((lq ^ (lr & 7)) << 4);
  const int o1 = lr * 128 + (((4 + lq) ^ (lr & 7)) << 4);
  const char* aB = smem + wm * 16384;                 // wave's A half base
  const char* bB = smem + 65536 + wn * 8192;          // wave's B sub-half base

#define BARX() asm volatile("s_waitcnt lgkmcnt(0)\n\ts_barrier" ::: "memory")
#define VMC4() asm volatile("s_waitcnt vmcnt(4)" ::: "memory")
#define VMC0() asm volatile("s_waitcnt vmcnt(0)" ::: "memory")
#define STG_A(tt, h, buf) do { \
    gl2lds16(a0 + (h) * 128 * lda + (tt) * 64, smem + (buf) * 32768 + (h) * 16384 + d0); \
    gl2lds16(a1 + (h) * 128 * lda + (tt) * 64, smem + (buf) * 32768 + (h) * 16384 + d1); } while (0)
#define STG_B(tt, h, buf) do { \
    gl2lds16(b0 + (h) * 128 * ldb + (tt) * 64, smem + 65536 + (buf) * 32768 + (h) * 16384 + d0); \
    gl2lds16(b1 + (h) * 128 * ldb + (tt) * 64, smem + 65536 + (buf) * 32768 + (h) * 16384 + d1); } while (0)
#define AF_(buf, mig, s) (*(const bf16x8*)(aB + (buf) * 32768 + (mig) * 2048 + o##s))
#define BF_(buf, nig, s) (*(const bf16x8*)(bB + (buf) * 32768 + (nig) * 2048 + o##s))
#define RD_BLO(buf) \
    _Pragma("unroll") \
    for (int ni = 0; ni < 2; ++ni) { bF[ni][0] = BF_(buf, ni, 0); bF[ni][1] = BF_(buf, ni, 1); }
#define RD_BHI(buf) \
    _Pragma("unroll") \
    for (int ni = 0; ni < 2; ++ni) { bF[ni][0] = BF_(buf, 2 + ni, 0); bF[ni][1] = BF_(buf, 2 + ni, 1); }
#define RD_ALO(buf) \
    _Pragma("unroll") \
    for (int mi = 0; mi < 4; ++mi) { aLo[mi][0] = AF_(buf, mi, 0); aLo[mi][1] = AF_(buf, mi, 1); }
#define RD_AHI(buf) \
    _Pragma("unroll") \
    for (int mi = 0; mi < 4; ++mi) { aHi[mi][0] = AF_(buf, 4 + mi, 0); aHi[mi][1] = AF_(buf, 4 + mi, 1); }
#define MFMA16(AR, M0, N0) \
    __builtin_amdgcn_s_setprio(1); \
    _Pragma("unroll") \
    for (int mi = 0; mi < 4; ++mi) \
      _Pragma("unroll") \
      for (int ni = 0; ni < 2; ++ni) { \
        acc[(M0) + mi][(N0) + ni] = __builtin_amdgcn_mfma_f32_16x16x32_bf16(AR[mi][0], bF[ni][0], acc[(M0) + mi][(N0) + ni], 0, 0, 0); \
        acc[(M0) + mi][(N0) + ni] = __builtin_amdgcn_mfma_f32_16x16x32_bf16(AR[mi][1], bF[ni][1], acc[(M0) + mi][(N0) + ni], 0, 0, 0); \
      } \
    __builtin_amdgcn_s_setprio(0);

  bf16x8 aLo[4][2], aHi[4][2], bF[2][2];

  // prologue: tile0 fully (buf0), tile1 A-halves (buf1) -> 12 loads, wait 8 oldest
  STG_A(0, 0, 0); STG_A(0, 1, 0); STG_B(0, 0, 0); STG_B(0, 1, 0);
  STG_A(1, 0, 1); STG_A(1, 1, 1);
  VMC4();
  asm volatile("s_barrier" ::: "memory");

  const int niter = (nt >> 1) - 1;   // main iterations; last pair is peeled
  for (int i = 0; i < niter; ++i) {
    const int t2 = 2 * i + 2, t3 = 2 * i + 3;
    // ---- phase 1: tile 2i (buf0), quad (Mlo,Nlo)
    RD_BLO(0) RD_ALO(0)
    STG_B(2 * i + 1, 0, 1);
    MFMA16(aLo, 0, 0)
    BARX();
    // ---- phase 2: (Mhi,Nlo)
    RD_AHI(0)
    STG_B(2 * i + 1, 1, 1);
    MFMA16(aHi, 4, 0)
    BARX();
    // ---- phase 3: (Mlo,Nhi)
    RD_BHI(0)
    STG_A(t2, 0, 0);
    MFMA16(aLo, 0, 2)
    BARX();
    // ---- phase 4: (Mhi,Nhi); counted vmcnt retires tile 2i+1
    STG_A(t2, 1, 0);
    MFMA16(aHi, 4, 2)
    VMC4();
    BARX();
    // ---- phase 5: tile 2i+1 (buf1), (Mlo,Nlo)
    RD_BLO(1) RD_ALO(1)
    STG_B(t2, 0, 0);
    MFMA16(aLo, 0, 0)
    BARX();
    // ---- phase 6: (Mhi,Nlo)
    RD_AHI(1)
    STG_B(t2, 1, 0);
    MFMA16(aHi, 4, 0)
    BARX();
    // ---- phase 7: (Mlo,Nhi)
    RD_BHI(1)
    STG_A(t3, 0, 1);
    MFMA16(aLo, 0, 2)
    BARX();
    // ---- phase 8: (Mhi,Nhi); counted vmcnt retires tile 2i+2
    STG_A(t3, 1, 1);
    MFMA16(aHi, 4, 2)
    VMC4();
    BARX();
  }
  // ---- peeled tail: tiles nt-2 (buf0) and nt-1 (buf1); only B(nt-1) stages
  {
    RD_BLO(0) RD_ALO(0)
    STG_B(nt - 1, 0, 1);
    MFMA16(aLo, 0, 0)
    BARX();
    RD_AHI(0)
    STG_B(nt - 1, 1, 1);
    MFMA16(aHi, 4, 0)
    BARX();
    RD_BHI(0)
    MFMA16(aLo, 0, 2)
    BARX();
    MFMA16(aHi, 4, 2)
    VMC0();                          // full drain: tile nt-1 resident (no later stages)
    BARX();
    RD_BLO(1) RD_ALO(1)
    MFMA16(aLo, 0, 0)
    BARX();
    RD_AHI(1)
    MFMA16(aHi, 4, 0)
    BARX();
    RD_BHI(1)
    MFMA16(aLo, 0, 2)
    BARX();
    MFMA16(aHi, 4, 2)
    BARX();
  }
#undef BARX
#undef VMC4
#undef VMC0
#undef STG_A
#undef STG_B
#undef AF_
#undef BF_
#undef RD_BLO
#undef RD_BHI
#undef RD_ALO
#undef RD_AHI
#undef MFMA16
}

// ---- fused projection: X[16384][1024] @ Wt[2048][1024]^T, grid 512 x 512thr ----
// n0 < 1024  -> Cq bf16 row-major (GATE: multiplied by gate)
// n0 >= 1024 -> K^T/V^T store via LDS-transposed (reuses the 128KB smem)
template <bool GATE>
__global__ __launch_bounds__(512, 2) void proj8(
    const ushort_t* __restrict__ X, const ushort_t* __restrict__ Wt,
    ushort_t* __restrict__ Cq, ushort_t* __restrict__ Ct,
    const ushort_t* __restrict__ gate) {
  extern __shared__ char smem[];
  const int bid = blockIdx.x;
  const int xcd = bid & 7, i = bid >> 3;        // XCD owns contiguous m-slab
  const int m0 = (xcd * 8 + (i >> 3)) * 256;
  const int n0 = (i & 7) * 256;
  f32x4 acc[8][4] = {};
  gemm256(X, 1024, Wt, 1024, m0, n0, 1024, smem, acc);

  const int t = threadIdx.x, lane = t & 63, wid = t >> 6;
  const int wm = wid >> 2, wn = wid & 3;
  const int lr = lane & 15, lq = lane >> 4;

  if (n0 < 1024) {
    #pragma unroll
    for (int mi = 0; mi < 8; ++mi) {
      int rbase = m0 + wm * 128 + mi * 16 + lq * 4;
      #pragma unroll
      for (int ni = 0; ni < 4; ++ni) {
        int c = n0 + wn * 64 + ni * 16 + lr;
        #pragma unroll
        for (int r = 0; r < 4; ++r) {
          float v = acc[mi][ni][r];
          if constexpr (GATE) v *= bf2f(gate[(size_t)(rbase + r) * 1024 + c]);
          Cq[(size_t)(rbase + r) * 1024 + c] = f2bf(v);
        }
      }
    }
  } else {
    __syncthreads();
    // stage C^T (d-major) in LDS: [256 d][256 ns], 16B-chunk xor swizzle
    #pragma unroll
    for (int mi = 0; mi < 8; ++mi) {
      int ns0 = wm * 128 + mi * 16 + lq * 4;          // local nseq, 4 consecutive
      int nc = ns0 >> 3, half8 = (ns0 >> 2) & 1;
      #pragma unroll
      for (int ni = 0; ni < 4; ++ni) {
        int dl = wn * 64 + ni * 16 + lr;              // local d
        ushort4 u = make_ushort4(f2bf(acc[mi][ni][0]), f2bf(acc[mi][ni][1]),
                                 f2bf(acc[mi][ni][2]), f2bf(acc[mi][ni][3]));
        *(ushort4*)(smem + dl * 512 + ((nc ^ (dl & 31)) * 16) + half8 * 8) = u;
      }
    }
    __syncthreads();
    const int b = m0 >> 12, nseq0 = m0 & 4095;
    #pragma unroll
    for (int j = 0; j < 16; ++j) {
      int g = j * 512 + t;
      int dl = g >> 5, nc = g & 31;
      bf16x8 v = *(const bf16x8*)(smem + dl * 512 + ((nc ^ (dl & 31)) * 16));
      int d = n0 - 1024 + dl;
      *(bf16x8*)&Ct[(((size_t)(b * 1024 + d)) << 12) + nseq0 + nc * 8] = v;
    }
  }
}

// ---- split-K KV, grid 256: XCD owns 2 z-slices; bf16 partials ----
__global__ __launch_bounds__(512, 2) void kv8(
    const ushort_t* __restrict__ VT, const ushort_t* __restrict__ KT,
    ushort_t* __restrict__ P) {
  extern __shared__ char smem[];
  const int bid = blockIdx.x;
  const int xcd = bid & 7, i = bid >> 3;        // i: 0..31
  const int z = xcd * 2 + (i >> 4);
  const int mn = i & 15;
  const int m0 = (mn >> 2) * 256, n0 = (mn & 3) * 256;
  const int b = z & 3, s = z >> 2;
  const ushort_t* A = VT + ((size_t)b << 22) + s * 1024;
  const ushort_t* Bt = KT + ((size_t)b << 22) + s * 1024;
  f32x4 acc[8][4] = {};
  gemm256(A, 4096, Bt, 4096, m0, n0, 1024, smem, acc);

  const int t = threadIdx.x, lane = t & 63, wid = t >> 6;
  const int wm = wid >> 2, wn = wid & 3;
  const int lr = lane & 15, lq = lane >> 4;
  ushort_t* C = P + ((size_t)z << 20);
  #pragma unroll
  for (int mi = 0; mi < 8; ++mi) {
    int rbase = m0 + wm * 128 + mi * 16 + lq * 4;
    #pragma unroll
    for (int ni = 0; ni < 4; ++ni) {
      int c = n0 + wn * 64 + ni * 16 + lr;
      #pragma unroll
      for (int r = 0; r < 4; ++r)
        C[(size_t)(rbase + r) * 1024 + c] = f2bf(acc[mi][ni][r]);
    }
  }
}

__global__ __launch_bounds__(256) void kv_reduce(const ushort_t* __restrict__ P,
                                                 ushort_t* __restrict__ KVT) {
  size_t e4 = ((size_t)blockIdx.x * 256 + threadIdx.x) * 4;  // < 4M
  int b = (int)(e4 >> 20);
  size_t j = e4 & ((1u << 20) - 1);
  float s0 = 0.f, s1 = 0.f, s2 = 0.f, s3 = 0.f;
  #pragma unroll
  for (int sp = 0; sp < 4; ++sp) {
    ushort4 v = *(const ushort4*)(P + ((size_t)(sp * 4 + b) << 20) + j);
    s0 += bf2f(v.x); s1 += bf2f(v.y); s2 += bf2f(v.z); s3 += bf2f(v.w);
  }
  *(ushort4*)&KVT[e4] = make_ushort4(f2bf(s0), f2bf(s1), f2bf(s2), f2bf(s3));
}

// ---- final: Out[m][e] = sum_d Q[m][d] * KVT[b(m)][e][d], fp32 out, grid 256 ----
__global__ __launch_bounds__(512, 2) void fin8(
    const ushort_t* __restrict__ Q, const ushort_t* __restrict__ KVT,
    float* __restrict__ Out) {
  extern __shared__ char smem[];
  const int bid = blockIdx.x;
  const int xcd = bid & 7, i = bid >> 3;        // i: 0..31
  const int m0 = (xcd * 8 + (i >> 2)) * 256;
  const int n0 = (i & 3) * 256;
  const int b = m0 >> 12;
  f32x4 acc[8][4] = {};
  gemm256(Q, 1024, KVT + ((size_t)b << 20), 1024, m0, n0, 1024, smem, acc);

  const int t = threadIdx.x, lane = t & 63, wid = t >> 6;
  const int wm = wid >> 2, wn = wid & 3;
  const int lr = lane & 15, lq = lane >> 4;
  #pragma unroll
  for (int mi = 0; mi < 8; ++mi) {
    int rbase = m0 + wm * 128 + mi * 16 + lq * 4;
    #pragma unroll
    for (int ni = 0; ni < 4; ++ni) {
      int c = n0 + wn * 64 + ni * 16 + lr;
      #pragma unroll
      for (int r = 0; r < 4; ++r)
        Out[(size_t)(rbase + r) * 1024 + c] = acc[mi][ni][r];
    }
  }
}

// ---- prep: 4x weight transpose+convert planes, then X fp32->bf16 ----
__global__ __launch_bounds__(256) void prep(
    const float* __restrict__ xr, const float* __restrict__ xi,
    const float* w0, const float* w1, const float* w2, const float* w3,
    ushort_t* __restrict__ xrb, ushort_t* __restrict__ xib,
    ushort_t* o0, ushort_t* o1, ushort_t* o2, ushort_t* o3) {
  const int bid = blockIdx.x;
  const int t = threadIdx.x;
  if (bid < 4096) {
    __shared__ float tile[32][33];
    const float* W; ushort_t* O;
    switch (bid >> 10) {
      case 0: W = w0; O = o0; break;
      case 1: W = w1; O = o1; break;
      case 2: W = w2; O = o2; break;
      default: W = w3; O = o3; break;
    }
    const int within = bid & 1023;
    const int bx = (within & 31) * 32, by = (within >> 5) * 32;
    const int tx = t & 31, ty = t >> 5;   // (32, 8)
    #pragma unroll
    for (int k = 0; k < 32; k += 8)
      tile[ty + k][tx] = W[(size_t)(by + ty + k) * 1024 + bx + tx];
    __syncthreads();
    #pragma unroll
    for (int k = 0; k < 32; k += 8)
      O[(size_t)(bx + ty + k) * 1024 + by + tx] = f2bf(tile[tx][ty + k]);
  } else {
    const size_t T = 16u * 1024u * 1024u;
    size_t e = ((size_t)(bid - 4096) * 256 + t) * 8;
    const float* src; ushort_t* dst;
    if (e < T) { src = xr + e; dst = xrb + e; }
    else       { src = xi + (e - T); dst = xib + (e - T); }
    float4 f0 = *(const float4*)src;
    float4 f1 = *(const float4*)(src + 4);
    ushort4 u0 = make_ushort4(f2bf(f0.x), f2bf(f0.y), f2bf(f0.z), f2bf(f0.w));
    ushort4 u1 = make_ushort4(f2bf(f1.x), f2bf(f1.y), f2bf(f1.z), f2bf(f1.w));
    *(ushort4*)dst = u0;
    *(ushort4*)(dst + 4) = u1;
  }
}

extern "C" void kernel_launch(void* const* d_in, const int* in_sizes, int n_in,
                              void* d_out, int out_size, void* d_ws, size_t ws_size,
                              hipStream_t stream) {
  const float* xr  = (const float*)d_in[0];
  const float* xi  = (const float*)d_in[1];
  const float* wqr = (const float*)d_in[2];
  const float* wqi = (const float*)d_in[3];
  const float* wk  = (const float*)d_in[4];
  const float* wv  = (const float*)d_in[5];

  char* ws = (char*)d_ws;
  const size_t MB = 1024ull * 1024ull;
  ushort_t* WtQR = (ushort_t*)(ws + 0 * MB);    // [WtQR;WtK] contiguous [2048][1024]
  ushort_t* WtK  = (ushort_t*)(ws + 2 * MB);
  ushort_t* WtQI = (ushort_t*)(ws + 4 * MB);    // [WtQI;WtV] contiguous
  ushort_t* WtV  = (ushort_t*)(ws + 6 * MB);
  ushort_t* Xrb  = (ushort_t*)(ws + 8 * MB);    // 32MB; dead after proj1 -> VT overlays
  ushort_t* Xib  = (ushort_t*)(ws + 40 * MB);   // 32MB; dead after proj2 -> KVT overlays
  ushort_t* KT   = (ushort_t*)(ws + 72 * MB);   // 32MB [4][1024][4096]
  ushort_t* Q    = (ushort_t*)(ws + 104 * MB);  // 32MB
  ushort_t* VT   = (ushort_t*)(ws + 8 * MB);    // overlay on Xrb
  ushort_t* KVT  = (ushort_t*)(ws + 40 * MB);   // overlay on Xib, 8MB
  ushort_t* QR   = (ushort_t*)d_out;            // bf16 scratch phase (32MB)
  ushort_t* KVP  = (ushort_t*)d_out;            // [16][1024][1024] bf16 = 32MB phase

  static bool inited = false;
  if (!inited) {
    inited = true;
    hipFuncSetAttribute((const void*)&proj8<false>, hipFuncAttributeMaxDynamicSharedMemorySize, 131072);
    hipFuncSetAttribute((const void*)&proj8<true>,  hipFuncAttributeMaxDynamicSharedMemorySize, 131072);
    hipFuncSetAttribute((const void*)&kv8,          hipFuncAttributeMaxDynamicSharedMemorySize, 131072);
    hipFuncSetAttribute((const void*)&fin8,         hipFuncAttributeMaxDynamicSharedMemorySize, 131072);
  }

  prep<<<20480, 256, 0, stream>>>(xr, xi, wqr, wqi, wk, wv,
                                  Xrb, Xib, WtQR, WtQI, WtK, WtV);
  proj8<false><<<512, 512, 131072, stream>>>(Xrb, WtQR, QR, KT, nullptr);
  proj8<true><<<512, 512, 131072, stream>>>(Xib, WtQI, Q, VT, QR);
  kv8<<<256, 512, 131072, stream>>>(VT, KT, KVP);
  kv_reduce<<<4096, 256, 0, stream>>>(KVP, KVT);
  fin8<<<256, 512, 131072, stream>>>(Q, KVT, (float*)d_out);
}